// Round 1
// baseline (365.773 us; speedup 1.0000x reference)
//
#include <hip/hip_runtime.h>
#include <math.h>

// B = 1048576 rows, C = 64 candidates, K = 4 signals, out = [B,1] fp32.
//
// Layout: 16 lanes per row (c = lane&15 covers columns 4c..4c+3 as float4),
// 4 rows per wave (g = lane>>4). Wave's 64 lanes read one contiguous 1 KiB
// chunk of x per iteration -> perfect coalescing. probs fragment (4 rows x
// 4 k) lives in registers per lane; 4-step shfl_xor butterfly reduces the
// 16 partial sums; epilogue (add-path + 16-leaf LUT contraction + mix)
// computed redundantly on all lanes; c==0 lanes store 4 consecutive floats.

__global__ __launch_bounds__(256) void LAB_42906723287350_kernel(
    const float* __restrict__ x,     // [B,64]
    const float* __restrict__ cp,    // [64,4] choice_parameters
    const float* __restrict__ lut,   // [2,2,2,2] flat 16
    const float* __restrict__ mixp,  // [3]
    float* __restrict__ out,         // [B]
    int nrow4)                       // B/4
{
    const int tid  = threadIdx.x;
    const int lane = tid & 63;
    const int c    = lane & 15;   // which column-quad of the row
    const int g    = lane >> 4;   // which row of the wave's 4 rows

    // ---------- tiny per-thread parameter precompute ----------
    // softmax over C (axis 0) of cp[64][4]; this lane needs rows 4c..4c+3.
    const float4* cp4 = (const float4*)cp;   // cp4[j] = cp[j][0..3]
    float sum0 = 0.f, sum1 = 0.f, sum2 = 0.f, sum3 = 0.f;
    #pragma unroll 8
    for (int j = 0; j < 64; ++j) {
        float4 v = cp4[j];
        sum0 += __expf(v.x); sum1 += __expf(v.y);
        sum2 += __expf(v.z); sum3 += __expf(v.w);
    }
    float p[4][4];   // p[i][k] = probs[4c+i][k]
    {
        const float i0 = 1.f/sum0, i1 = 1.f/sum1, i2 = 1.f/sum2, i3 = 1.f/sum3;
        #pragma unroll
        for (int i = 0; i < 4; ++i) {
            float4 v = cp4[c*4 + i];
            p[i][0] = __expf(v.x)*i0;
            p[i][1] = __expf(v.y)*i1;
            p[i][2] = __expf(v.z)*i2;
            p[i][3] = __expf(v.w)*i3;
        }
    }
    // sigmoid(lut): precompute level-1 (bit l) fma coefficients.
    float lsd[8], lsb[8];
    #pragma unroll
    for (int m = 0; m < 8; ++m) {
        float a = 1.f / (1.f + __expf(-lut[2*m]));
        float b = 1.f / (1.f + __expf(-lut[2*m+1]));
        lsd[m] = a - b;   // * s3
        lsb[m] = b;       // + (1-s3) part
    }
    // mix = softmax(lut_vs_add_choice_parameters)
    float m0 = __expf(mixp[0]), m1 = __expf(mixp[1]), m2 = __expf(mixp[2]);
    const float minv = 1.f / (m0 + m1 + m2);
    m0 *= minv; m1 *= minv; m2 *= minv;

    // ---------- main loop: 4 rows (1 KiB of x) per wave per iter ----------
    const int waveId = (blockIdx.x * blockDim.x + tid) >> 6;
    const int nWaves = (gridDim.x * blockDim.x) >> 6;
    const float4* x4 = (const float4*)x;   // row stride = 16 float4s

    for (int r4 = waveId; r4 < nrow4; r4 += nWaves) {
        // lane (g,c): row = r4*4+g, cols 4c..4c+3. Wave = contiguous 1 KiB.
        float4 xv = x4[(size_t)r4 * 64 + (size_t)(g * 16 + c)];

        float s0 = fmaf(xv.x, p[0][0], fmaf(xv.y, p[1][0], fmaf(xv.z, p[2][0], xv.w * p[3][0])));
        float s1 = fmaf(xv.x, p[0][1], fmaf(xv.y, p[1][1], fmaf(xv.z, p[2][1], xv.w * p[3][1])));
        float s2 = fmaf(xv.x, p[0][2], fmaf(xv.y, p[1][2], fmaf(xv.z, p[2][2], xv.w * p[3][2])));
        float s3 = fmaf(xv.x, p[0][3], fmaf(xv.y, p[1][3], fmaf(xv.z, p[2][3], xv.w * p[3][3])));

        // butterfly sum across the 16 lanes of this row (masks stay in-group)
        #pragma unroll
        for (int off = 1; off < 16; off <<= 1) {
            s0 += __shfl_xor(s0, off);
            s1 += __shfl_xor(s1, off);
            s2 += __shfl_xor(s2, off);
            s3 += __shfl_xor(s3, off);
        }

        // addition path
        float add = s0 + s1 + s2;
        float a1  = fminf(fmaxf(add - 2.f, 0.f), 1.f);
        float a2  = (add >= 2.f) ? 1.f : 0.f;

        // multilinear LUT contraction over the 16 sigmoid leaves
        float t8[8];
        #pragma unroll
        for (int m = 0; m < 8; ++m) t8[m] = fmaf(s3, lsd[m], lsb[m]);
        float t4[4];
        #pragma unroll
        for (int n = 0; n < 4; ++n) t4[n] = fmaf(s2, t8[2*n] - t8[2*n+1], t8[2*n+1]);
        float t2[2];
        #pragma unroll
        for (int n = 0; n < 2; ++n) t2[n] = fmaf(s1, t4[2*n] - t4[2*n+1], t4[2*n+1]);
        float lut_out = fmaf(s0, t2[0] - t2[1], t2[1]);

        float res = m0 * lut_out + m1 * a1 + m2 * a2;

        if (c == 0) out[r4 * 4 + g] = res;   // 4 consecutive dwords per wave
    }
}

extern "C" void kernel_launch(void* const* d_in, const int* in_sizes, int n_in,
                              void* d_out, int out_size, void* d_ws, size_t ws_size,
                              hipStream_t stream) {
    const float* x    = (const float*)d_in[0];
    const float* cp   = (const float*)d_in[1];
    const float* lut  = (const float*)d_in[2];
    const float* mixp = (const float*)d_in[3];
    float* out = (float*)d_out;

    const int nrow4 = out_size / 4;           // B/4 = 262144
    const int block = 256;
    const int grid  = 2048;                   // 8 blocks/CU, grid-stride loop

    LAB_42906723287350_kernel<<<grid, block, 0, stream>>>(x, cp, lut, mixp, out, nrow4);
}

// Round 2
// 361.308 us; speedup vs baseline: 1.0124x; 1.0124x over previous
//
#include <hip/hip_runtime.h>
#include <math.h>

// B = 1048576 rows, C = 64, K = 4. out = [B,1] fp32.
//
// 16 lanes per row (c = lane&15 -> columns 4c..4c+3 as float4), 4 rows per
// wave (g = lane>>4). Wave reads one contiguous 1 KiB chunk of x per group.
// Reduction across the 16 lanes of a row uses DPP row ops (quad_perm xor1,
// xor2, row_half_mirror, row_mirror) on the VALU pipe -- zero DS ops, no
// lgkmcnt chain (round 1 used ds_swizzle shuffles: ~95k DS cyc/CU > the
// ~43k cyc/CU HBM floor). Two row-groups are processed per loop iteration
// so two 1 KiB loads are in flight per wave.

template <int CTRL>
__device__ __forceinline__ float dpp_add(float v) {
    int y = __builtin_amdgcn_update_dpp(0, __float_as_int(v), CTRL, 0xF, 0xF, true);
    return v + __int_as_float(y);
}

// Sum across the 16 lanes of a DPP "row"; every lane gets the total.
// (lane&15 groups never cross DPP row boundaries.)
__device__ __forceinline__ float row16_sum(float v) {
    v = dpp_add<0xB1>(v);   // quad_perm [1,0,3,2]  : xor 1
    v = dpp_add<0x4E>(v);   // quad_perm [2,3,0,1]  : xor 2
    v = dpp_add<0x141>(v);  // row_half_mirror      : pairs across quads in 8
    v = dpp_add<0x140>(v);  // row_mirror           : pairs across 8-halves
    return v;
}

__global__ __launch_bounds__(256) void LAB_42906723287350_kernel(
    const float* __restrict__ x,     // [B,64]
    const float* __restrict__ cp,    // [64,4]
    const float* __restrict__ lut,   // [16]
    const float* __restrict__ mixp,  // [3]
    float* __restrict__ out,         // [B]
    int nrow4)                       // B/4
{
    const int tid  = threadIdx.x;
    const int lane = tid & 63;
    const int c    = lane & 15;
    const int g    = lane >> 4;

    // ---------- parameter precompute (cooperative softmax over C) ----------
    const float4* cp4 = (const float4*)cp;   // cp4[j] = cp[j][0..3]
    float e[4][4];                            // exp(cp[4c+i][k])
    float sum0 = 0.f, sum1 = 0.f, sum2 = 0.f, sum3 = 0.f;
    #pragma unroll
    for (int i = 0; i < 4; ++i) {
        float4 v = cp4[c * 4 + i];
        e[i][0] = __expf(v.x); e[i][1] = __expf(v.y);
        e[i][2] = __expf(v.z); e[i][3] = __expf(v.w);
        sum0 += e[i][0]; sum1 += e[i][1]; sum2 += e[i][2]; sum3 += e[i][3];
    }
    sum0 = row16_sum(sum0); sum1 = row16_sum(sum1);
    sum2 = row16_sum(sum2); sum3 = row16_sum(sum3);
    float p[4][4];                            // probs[4c+i][k]
    {
        const float i0 = 1.f/sum0, i1 = 1.f/sum1, i2 = 1.f/sum2, i3 = 1.f/sum3;
        #pragma unroll
        for (int i = 0; i < 4; ++i) {
            p[i][0] = e[i][0]*i0; p[i][1] = e[i][1]*i1;
            p[i][2] = e[i][2]*i2; p[i][3] = e[i][3]*i3;
        }
    }
    // sigmoid(lut) level-1 fma coefficients
    float lsd[8], lsb[8];
    #pragma unroll
    for (int m = 0; m < 8; ++m) {
        float a = 1.f / (1.f + __expf(-lut[2*m]));
        float b = 1.f / (1.f + __expf(-lut[2*m+1]));
        lsd[m] = a - b;
        lsb[m] = b;
    }
    float m0 = __expf(mixp[0]), m1 = __expf(mixp[1]), m2 = __expf(mixp[2]);
    const float minv = 1.f / (m0 + m1 + m2);
    m0 *= minv; m1 *= minv; m2 *= minv;

    // ---------- main loop: 2 row-groups (2 x 1 KiB) in flight per wave ----
    const int waveId = (blockIdx.x * blockDim.x + tid) >> 6;
    const int nWaves = (gridDim.x * blockDim.x) >> 6;
    const float4* x4 = (const float4*)x;
    const int laneOff = g * 16 + c;

    for (int r4 = waveId; r4 < nrow4; r4 += 2 * nWaves) {
        const int r4b = r4 + nWaves;
        const bool hasb = (r4b < nrow4);          // wave-uniform

        float4 xa = x4[(size_t)r4 * 64 + laneOff];
        float4 xb = hasb ? x4[(size_t)r4b * 64 + laneOff]
                         : make_float4(0.f, 0.f, 0.f, 0.f);

        #pragma unroll
        for (int half = 0; half < 2; ++half) {
            if (half == 1 && !hasb) break;
            const float4 xv = (half == 0) ? xa : xb;
            const int    rr = (half == 0) ? r4 : r4b;

            float s0 = fmaf(xv.x, p[0][0], fmaf(xv.y, p[1][0], fmaf(xv.z, p[2][0], xv.w * p[3][0])));
            float s1 = fmaf(xv.x, p[0][1], fmaf(xv.y, p[1][1], fmaf(xv.z, p[2][1], xv.w * p[3][1])));
            float s2 = fmaf(xv.x, p[0][2], fmaf(xv.y, p[1][2], fmaf(xv.z, p[2][2], xv.w * p[3][2])));
            float s3 = fmaf(xv.x, p[0][3], fmaf(xv.y, p[1][3], fmaf(xv.z, p[2][3], xv.w * p[3][3])));

            s0 = row16_sum(s0);
            s1 = row16_sum(s1);
            s2 = row16_sum(s2);
            s3 = row16_sum(s3);

            // addition path
            float add = s0 + s1 + s2;
            float a1  = fminf(fmaxf(add - 2.f, 0.f), 1.f);
            float a2  = (add >= 2.f) ? 1.f : 0.f;

            // 16-leaf multilinear LUT contraction
            float t8[8];
            #pragma unroll
            for (int m = 0; m < 8; ++m) t8[m] = fmaf(s3, lsd[m], lsb[m]);
            float t4[4];
            #pragma unroll
            for (int n = 0; n < 4; ++n) t4[n] = fmaf(s2, t8[2*n] - t8[2*n+1], t8[2*n+1]);
            float t2[2];
            #pragma unroll
            for (int n = 0; n < 2; ++n) t2[n] = fmaf(s1, t4[2*n] - t4[2*n+1], t4[2*n+1]);
            float lut_out = fmaf(s0, t2[0] - t2[1], t2[1]);

            float res = m0 * lut_out + m1 * a1 + m2 * a2;

            if (c == 0) out[rr * 4 + g] = res;
        }
    }
}

extern "C" void kernel_launch(void* const* d_in, const int* in_sizes, int n_in,
                              void* d_out, int out_size, void* d_ws, size_t ws_size,
                              hipStream_t stream) {
    const float* x    = (const float*)d_in[0];
    const float* cp   = (const float*)d_in[1];
    const float* lut  = (const float*)d_in[2];
    const float* mixp = (const float*)d_in[3];
    float* out = (float*)d_out;

    const int nrow4 = out_size / 4;   // B/4 = 262144
    const int block = 256;
    const int grid  = 2048;           // 8 blocks/CU, grid-stride

    LAB_42906723287350_kernel<<<grid, block, 0, stream>>>(x, cp, lut, mixp, out, nrow4);
}

// Round 3
// 348.877 us; speedup vs baseline: 1.0484x; 1.0356x over previous
//
#include <hip/hip_runtime.h>
#include <math.h>

// B = 1048576 rows, C = 64, K = 4. out = [B,1] fp32.
//
// 16 lanes per row (c = lane&15 -> columns 4c..4c+3 as float4), 4 rows per
// wave (g = lane>>4); wave reads one contiguous 1 KiB chunk per row-group.
// Row reduction via DPP row ops (VALU pipe, zero DS traffic). Round-3: keep
// FOUR row-groups (4 KiB) in flight per wave (was 2) and use non-temporal
// loads for x (single-use stream, skip cache allocation). Kernel floor is
// ~41 us (272 MB @ 6.65 TB/s); harness restore/poison (~300 us) dominates
// the reported dur_us and is outside our control.

typedef float vfloat4 __attribute__((ext_vector_type(4)));

template <int CTRL>
__device__ __forceinline__ float dpp_add(float v) {
    int y = __builtin_amdgcn_update_dpp(0, __float_as_int(v), CTRL, 0xF, 0xF, true);
    return v + __int_as_float(y);
}

// Sum across the 16 lanes of a DPP "row"; every lane gets the total.
__device__ __forceinline__ float row16_sum(float v) {
    v = dpp_add<0xB1>(v);   // quad_perm xor1
    v = dpp_add<0x4E>(v);   // quad_perm xor2
    v = dpp_add<0x141>(v);  // row_half_mirror
    v = dpp_add<0x140>(v);  // row_mirror
    return v;
}

__global__ __launch_bounds__(256) void LAB_42906723287350_kernel(
    const float* __restrict__ x,     // [B,64]
    const float* __restrict__ cp,    // [64,4]
    const float* __restrict__ lut,   // [16]
    const float* __restrict__ mixp,  // [3]
    float* __restrict__ out,         // [B]
    int nrow4)                       // B/4
{
    const int tid  = threadIdx.x;
    const int lane = tid & 63;
    const int c    = lane & 15;
    const int g    = lane >> 4;

    // ---------- parameter precompute (cooperative softmax over C) ----------
    const vfloat4* cp4 = (const vfloat4*)cp;
    float e[4][4];
    float sum0 = 0.f, sum1 = 0.f, sum2 = 0.f, sum3 = 0.f;
    #pragma unroll
    for (int i = 0; i < 4; ++i) {
        vfloat4 v = cp4[c * 4 + i];
        e[i][0] = __expf(v.x); e[i][1] = __expf(v.y);
        e[i][2] = __expf(v.z); e[i][3] = __expf(v.w);
        sum0 += e[i][0]; sum1 += e[i][1]; sum2 += e[i][2]; sum3 += e[i][3];
    }
    sum0 = row16_sum(sum0); sum1 = row16_sum(sum1);
    sum2 = row16_sum(sum2); sum3 = row16_sum(sum3);
    float p[4][4];
    {
        const float i0 = 1.f/sum0, i1 = 1.f/sum1, i2 = 1.f/sum2, i3 = 1.f/sum3;
        #pragma unroll
        for (int i = 0; i < 4; ++i) {
            p[i][0] = e[i][0]*i0; p[i][1] = e[i][1]*i1;
            p[i][2] = e[i][2]*i2; p[i][3] = e[i][3]*i3;
        }
    }
    // sigmoid(lut) level-1 fma coefficients
    float lsd[8], lsb[8];
    #pragma unroll
    for (int m = 0; m < 8; ++m) {
        float a = 1.f / (1.f + __expf(-lut[2*m]));
        float b = 1.f / (1.f + __expf(-lut[2*m+1]));
        lsd[m] = a - b;
        lsb[m] = b;
    }
    float m0 = __expf(mixp[0]), m1 = __expf(mixp[1]), m2 = __expf(mixp[2]);
    const float minv = 1.f / (m0 + m1 + m2);
    m0 *= minv; m1 *= minv; m2 *= minv;

    // ---------- main loop: 4 row-groups (4 KiB) in flight per wave --------
    const int waveId = (blockIdx.x * blockDim.x + tid) >> 6;
    const int nWaves = (gridDim.x * blockDim.x) >> 6;
    const vfloat4* x4 = (const vfloat4*)x;
    const int laneOff = g * 16 + c;

    for (int r4 = waveId; r4 < nrow4; r4 += 4 * nWaves) {
        int rr[4];
        vfloat4 xv[4];
        #pragma unroll
        for (int u = 0; u < 4; ++u) {
            rr[u] = r4 + u * nWaves;
            if (rr[u] < nrow4)
                xv[u] = __builtin_nontemporal_load(
                            x4 + (size_t)rr[u] * 64 + laneOff);
        }

        #pragma unroll
        for (int u = 0; u < 4; ++u) {
            if (rr[u] >= nrow4) break;   // wave-uniform
            const vfloat4 v = xv[u];

            float s0 = fmaf(v.x, p[0][0], fmaf(v.y, p[1][0], fmaf(v.z, p[2][0], v.w * p[3][0])));
            float s1 = fmaf(v.x, p[0][1], fmaf(v.y, p[1][1], fmaf(v.z, p[2][1], v.w * p[3][1])));
            float s2 = fmaf(v.x, p[0][2], fmaf(v.y, p[1][2], fmaf(v.z, p[2][2], v.w * p[3][2])));
            float s3 = fmaf(v.x, p[0][3], fmaf(v.y, p[1][3], fmaf(v.z, p[2][3], v.w * p[3][3])));

            s0 = row16_sum(s0);
            s1 = row16_sum(s1);
            s2 = row16_sum(s2);
            s3 = row16_sum(s3);

            // addition path
            float add = s0 + s1 + s2;
            float a1  = fminf(fmaxf(add - 2.f, 0.f), 1.f);
            float a2  = (add >= 2.f) ? 1.f : 0.f;

            // 16-leaf multilinear LUT contraction
            float t8[8];
            #pragma unroll
            for (int m = 0; m < 8; ++m) t8[m] = fmaf(s3, lsd[m], lsb[m]);
            float t4[4];
            #pragma unroll
            for (int n = 0; n < 4; ++n) t4[n] = fmaf(s2, t8[2*n] - t8[2*n+1], t8[2*n+1]);
            float t2[2];
            #pragma unroll
            for (int n = 0; n < 2; ++n) t2[n] = fmaf(s1, t4[2*n] - t4[2*n+1], t4[2*n+1]);
            float lut_out = fmaf(s0, t2[0] - t2[1], t2[1]);

            float res = m0 * lut_out + m1 * a1 + m2 * a2;

            if (c == 0) out[rr[u] * 4 + g] = res;
        }
    }
}

extern "C" void kernel_launch(void* const* d_in, const int* in_sizes, int n_in,
                              void* d_out, int out_size, void* d_ws, size_t ws_size,
                              hipStream_t stream) {
    const float* x    = (const float*)d_in[0];
    const float* cp   = (const float*)d_in[1];
    const float* lut  = (const float*)d_in[2];
    const float* mixp = (const float*)d_in[3];
    float* out = (float*)d_out;

    const int nrow4 = out_size / 4;   // B/4 = 262144
    const int block = 256;
    const int grid  = 2048;           // 8192 waves: 32 groups/wave, 8 iters

    LAB_42906723287350_kernel<<<grid, block, 0, stream>>>(x, cp, lut, mixp, out, nrow4);
}